// Round 6
// baseline (276.264 us; speedup 1.0000x reference)
//
#include <hip/hip_runtime.h>
#include <stdint.h>

// GPT-2 attention block, bf16 MFMA. Round 6:
//  - flash: split-kv chunks (<=16 kt-iters) with EXACTLY-mergeable fixed-m
//    partials (O,l additive over disjoint kv); last-finisher merges in-register
//    via device-scope flag; 768 blocks (3/CU), atomic work queue, heavy-first.
//  - GEMMs: 3-buffer LDS, 2-deep prefetch, counted vmcnt(8) (covers L2/L3 lat).
//  - scratch for partials aliases hsb (dead after QKV GEMM).

constexpr int B_  = 2;
constexpr int S_  = 2048;
constexpr int D_  = 768;
constexpr int N3D = 3 * D_;   // 2304
constexpr int M_  = B_ * S_;  // 4096
constexpr int NCHUNK = 1152;  // 24 bh * 48 tiers (split tiles contribute 2)
#define QSCALE 0.1803368801111f   // 1/sqrt(64) * log2(e)
#define FIXED_M 8.0f

typedef __bf16 bv8 __attribute__((ext_vector_type(8)));
typedef float  fv4 __attribute__((ext_vector_type(4)));
typedef unsigned short uv4 __attribute__((ext_vector_type(4)));
typedef unsigned short uv8 __attribute__((ext_vector_type(8)));

__device__ inline unsigned short f2bf(float x) {
    __bf16 b = (__bf16)x;
    return __builtin_bit_cast(unsigned short, b);
}

__device__ inline fv4 mfma16(bv8 a, bv8 b, fv4 c) {
    return __builtin_amdgcn_mfma_f32_16x16x32_bf16(a, b, c, 0, 0, 0);
}

#define GLOAD_LDS16(g, l)                                                        \
    __builtin_amdgcn_global_load_lds(                                            \
        (__attribute__((address_space(1))) void*)(g),                            \
        (__attribute__((address_space(3))) void*)(l), 16, 0, 0)

#define VMCNT8() asm volatile("s_waitcnt vmcnt(8)" ::: "memory")
#define VMCNT4() asm volatile("s_waitcnt vmcnt(4)" ::: "memory")
#define VMCNT0() asm volatile("s_waitcnt vmcnt(0)" ::: "memory")
#define BAR()                                                                    \
    do { asm volatile("" ::: "memory"); __builtin_amdgcn_s_barrier();            \
         asm volatile("" ::: "memory"); } while (0)

// ---------------------------------------------------------------------------
// Fused prep: [0,1536) cvt hs->bf16 ; [1536,3264) wqkv^T ; [3264,3840) wproj^T
// Block 0 zeroes the queue counter + split flags (cnt[0..387]).
// ---------------------------------------------------------------------------
__global__ __launch_bounds__(256)
void prep(const float* __restrict__ hs, const float* __restrict__ wqkv,
          const float* __restrict__ wproj, unsigned short* __restrict__ hsb,
          unsigned short* __restrict__ wqkvT, unsigned short* __restrict__ wprojT,
          int* __restrict__ cnt)
{
    __shared__ float tl[32][33];
    const int bid = blockIdx.x, t = threadIdx.x;
    if (bid == 0) {
        for (int i = t; i < 388; i += 256) cnt[i] = 0;
    }

    if (bid < 1536) {
        const size_t i = ((size_t)bid * 256 + t) * 8;
        const float4 a = *(const float4*)&hs[i];
        const float4 b = *(const float4*)&hs[i + 4];
        uv8 o;
        o[0] = f2bf(a.x); o[1] = f2bf(a.y); o[2] = f2bf(a.z); o[3] = f2bf(a.w);
        o[4] = f2bf(b.x); o[5] = f2bf(b.y); o[6] = f2bf(b.z); o[7] = f2bf(b.w);
        *(uv8*)&hsb[i] = o;
        return;
    }

    const float* W;
    unsigned short* WT;
    int K, N, bx, by;
    if (bid < 3264) {
        W = wqkv; WT = wqkvT; K = 768; N = 2304;
        const int b2 = bid - 1536; bx = b2 % 72; by = b2 / 72;
    } else {
        W = wproj; WT = wprojT; K = 768; N = 768;
        const int b2 = bid - 3264; bx = b2 % 24; by = b2 / 24;
    }
    const int n0 = bx * 32, k0 = by * 32;
    {
        const int r = t >> 3, c = (t & 7) * 4;
        const float4 v = *(const float4*)&W[(size_t)(k0 + r) * N + n0 + c];
        tl[r][c + 0] = v.x; tl[r][c + 1] = v.y; tl[r][c + 2] = v.z; tl[r][c + 3] = v.w;
    }
    __syncthreads();
    {
        const int rn = t >> 3, ck = (t & 7) * 4;
        uv4 o;
        o[0] = f2bf(tl[ck + 0][rn]); o[1] = f2bf(tl[ck + 1][rn]);
        o[2] = f2bf(tl[ck + 2][rn]); o[3] = f2bf(tl[ck + 3][rn]);
        *(uv4*)&WT[(size_t)(n0 + rn) * K + k0 + ck] = o;
    }
}

// ---------------------------------------------------------------------------
// bf16 MFMA GEMM, 128x128 tile, BK=32, THREE LDS buffers, 2-deep prefetch
// (vmcnt(8): tile-t loads have had 2 full iters to land -> L2/L3 lat covered).
// QKV=true : Q (x QSCALE) / K repacked through LDS for coalesced b128 stores;
//            V^T b64 scatter. QKV=false: fp32 row-major C.
// ---------------------------------------------------------------------------
template<bool QKV>
__global__ __launch_bounds__(256)
void gemm_bf16(const unsigned short* __restrict__ A, const unsigned short* __restrict__ BT,
               const float* __restrict__ bias, float* __restrict__ Cf,
               unsigned short* __restrict__ Qb, unsigned short* __restrict__ Kb,
               unsigned short* __restrict__ VTb, int M, int N, int K)
{
    __shared__ unsigned short smem[24576];   // sA[3] | sB[3]; epilogue reuses 32KB
    unsigned short* const sA0 = smem;
    unsigned short* const sB0 = smem + 12288;

    const int t = threadIdx.x, w = t >> 6, lane = t & 63;
    const int l15 = lane & 15, l4 = lane >> 4;
    const int m0 = blockIdx.y * 128, n0 = blockIdx.x * 128;
    const int wr = w >> 1, wc = w & 1;

    fv4 acc[4][4];
#pragma unroll
    for (int i = 0; i < 4; ++i)
#pragma unroll
        for (int j = 0; j < 4; ++j) acc[i][j] = fv4{0.f, 0.f, 0.f, 0.f};

    const int r0 = w * 16 + (lane >> 2);
    const int c0 = (lane & 3) ^ ((r0 >> 1) & 3);
    const int r1 = (w + 4) * 16 + (lane >> 2);
    const int c1 = (lane & 3) ^ ((r1 >> 1) & 3);

    auto stage = [&](int buf, int k0) {
        GLOAD_LDS16(A  + (size_t)(m0 + r0) * K + k0 + c0 * 8, sA0 + buf * 4096 + w * 512);
        GLOAD_LDS16(A  + (size_t)(m0 + r1) * K + k0 + c1 * 8, sA0 + buf * 4096 + (w + 4) * 512);
        GLOAD_LDS16(BT + (size_t)(n0 + r0) * K + k0 + c0 * 8, sB0 + buf * 4096 + w * 512);
        GLOAD_LDS16(BT + (size_t)(n0 + r1) * K + k0 + c1 * 8, sB0 + buf * 4096 + (w + 4) * 512);
    };

    stage(0, 0);
    stage(1, 32);
    const int nt = K >> 5;
    int cur = 0, sb = 2;
    for (int tt = 0; tt < nt; ++tt) {
        if (tt + 2 < nt) { stage(sb, (tt + 2) * 32); sb = (sb == 2) ? 0 : sb + 1; VMCNT8(); }
        else if (tt + 1 < nt) VMCNT4();
        else VMCNT0();
        BAR();

        bv8 af[4], bf[4];
#pragma unroll
        for (int i = 0; i < 4; ++i) {
            const int r = wr * 64 + i * 16 + l15;
            const int c = l4 ^ ((r >> 1) & 3);
            af[i] = *(const bv8*)&sA0[cur * 4096 + r * 32 + c * 8];
        }
#pragma unroll
        for (int j = 0; j < 4; ++j) {
            const int r = wc * 64 + j * 16 + l15;
            const int c = l4 ^ ((r >> 1) & 3);
            bf[j] = *(const bv8*)&sB0[cur * 4096 + r * 32 + c * 8];
        }
        __builtin_amdgcn_s_setprio(1);
#pragma unroll
        for (int i = 0; i < 4; ++i)
#pragma unroll
            for (int j = 0; j < 4; ++j)
                acc[i][j] = mfma16(af[i], bf[j], acc[i][j]);
        __builtin_amdgcn_s_setprio(0);
        BAR();
        cur = (cur == 2) ? 0 : cur + 1;
    }

    if (QKV) {
        const int sect = n0 / 768;           // uniform per block (768 % 128 == 0)
        const int rem0 = n0 - sect * 768;
        if (sect < 2) {
            const float qs = (sect == 0) ? QSCALE : 1.0f;
#pragma unroll
            for (int jf = 0; jf < 4; ++jf) {
                const int c = wc * 64 + jf * 16 + l15;
                const float bb = bias[n0 + c];
                const int ch = c >> 3, off = c & 7;
#pragma unroll
                for (int i = 0; i < 4; ++i) {
                    const int rb = wr * 64 + i * 16 + l4 * 4;
#pragma unroll
                    for (int reg = 0; reg < 4; ++reg) {
                        const int r = rb + reg;
                        smem[r * 128 + ((ch ^ (r & 15)) << 3) + off] =
                            f2bf((acc[i][jf][reg] + bb) * qs);
                    }
                }
            }
            __syncthreads();
            unsigned short* const dstQK = (sect == 0) ? Qb : Kb;
            const int brow = m0 >> 11, sbase = m0 & 2047, hb = rem0 >> 6;
#pragma unroll
            for (int u = 0; u < 8; ++u) {
                const int ID = t + 256 * u;
                const int s = ID >> 4, ch = ID & 15;
                const int hh = ch >> 3, dc = ch & 7;
                const uv8 v = *(const uv8*)&smem[s * 128 + ((ch ^ (s & 15)) << 3)];
                const size_t bh = (size_t)brow * 12 + hb + hh;
                *(uv8*)&dstQK[(bh * 2048 + sbase + s) * 64 + dc * 8] = v;
            }
        } else {
#pragma unroll
            for (int jf = 0; jf < 4; ++jf) {
                const int col = n0 + wc * 64 + jf * 16 + l15;
                const float bb = bias[col];
                const int rem = col - 2 * 768;
                const int hh_ = rem >> 6, d = rem & 63;
#pragma unroll
                for (int i = 0; i < 4; ++i) {
                    const int rowb = m0 + wr * 64 + i * 16 + l4 * 4;
                    const size_t bh = (size_t)(rowb >> 11) * 12 + hh_;
                    const int s0 = rowb & 2047;
                    uv4 pk;
#pragma unroll
                    for (int reg = 0; reg < 4; ++reg) pk[reg] = f2bf(acc[i][jf][reg] + bb);
                    *(uv4*)&VTb[(bh * 64 + d) * 2048 + s0] = pk;
                }
            }
        }
    } else {
#pragma unroll
        for (int jf = 0; jf < 4; ++jf) {
            const int col = n0 + wc * 64 + jf * 16 + l15;
            const float bb = bias[col];
#pragma unroll
            for (int i = 0; i < 4; ++i) {
                const int rowb = m0 + wr * 64 + i * 16 + l4 * 4;
#pragma unroll
                for (int reg = 0; reg < 4; ++reg)
                    Cf[(size_t)(rowb + reg) * N + col] = acc[i][jf][reg] + bb;
            }
        }
    }
}

// ---------------------------------------------------------------------------
// Flash attention (causal), S^T-swapped MFMA, FIXED-m exp2 softmax.
// Work unit = chunk: (qt, bh, kv-range of <=16 kt-iters). Fixed-m partials
// over disjoint kv are exactly additive -> split tiles (qt>=16) use 2 chunks;
// first finisher writes fp32 (O,l) to scratch, last finisher merges in-register.
// Chunk order is heavy-first; 768 persistent blocks, atomic queue.
// ---------------------------------------------------------------------------
__global__ __launch_bounds__(256)
void flash_mfma(const unsigned short* __restrict__ Qb, const unsigned short* __restrict__ Kb,
                const unsigned short* __restrict__ VTb, unsigned short* __restrict__ outb,
                int* __restrict__ cnt, int* __restrict__ flags,
                float* __restrict__ scrO, float* __restrict__ scrL)
{
    __shared__ unsigned short sK [2][64 * 64];
    __shared__ unsigned short sVT[2][64 * 64];
    __shared__ unsigned short sP [4][16 * 64];
    __shared__ int sComm;

    const int t = threadIdx.x, w = t >> 6, lane = t & 63;
    const int l15 = lane & 15, l4 = lane >> 4;

    const int sr0 = w * 8 + (lane >> 3), sc0 = (lane & 7) ^ (sr0 & 7);
    const int sr1 = (w + 4) * 8 + (lane >> 3), sc1 = (lane & 7) ^ (sr1 & 7);

    for (;;) {
        if (t == 0) sComm = atomicAdd(cnt, 1);
        __syncthreads();
        const int j = sComm;
        if (j >= NCHUNK) return;

        // ---- decode chunk j -> (qt, bh, kt range, split?) heavy-first ----
        const int tier = j / 24;
        const int bh = j - tier * 24;
        int qt, k0, k1, split;
        if (tier < 16)       { qt = 31 - tier; k0 = 0;  k1 = 15; split = 1; }
        else if (tier == 16) { qt = 31;        k0 = 16; k1 = 31; split = 1; }
        else if (tier == 17) { qt = 15;        k0 = 0;  k1 = 15; split = 0; }
        else {
            const int u = tier - 18, s = 15 - (u >> 1);
            if ((u & 1) == 0) { qt = 15 + s; k0 = 16; k1 = qt; split = 1; }
            else              { qt = s - 1;  k0 = 0;  k1 = qt; split = 0; }
        }
        const int b = bh / 12, h = bh - b * 12;
        const int qrow = qt * 64 + w * 16;

        const unsigned short* Kbase = Kb  + (size_t)bh * 2048 * 64;
        const unsigned short* Vbase = VTb + (size_t)bh * 64 * 2048;

        bv8 qf[2];
        {
            const unsigned short* qp = Qb + ((size_t)bh * 2048 + qrow + l15) * 64 + l4 * 8;
            qf[0] = *(const bv8*)qp;
            qf[1] = *(const bv8*)(qp + 32);
        }

        fv4 o[4];
#pragma unroll
        for (int jf = 0; jf < 4; ++jf) o[jf] = fv4{0.f, 0.f, 0.f, 0.f};
        float l_ = 0.f;

        // prologue stage for kt = k0
        GLOAD_LDS16(Kbase + (size_t)(k0 * 64 + sr0) * 64 + sc0 * 8, &sK[0][w * 512]);
        GLOAD_LDS16(Kbase + (size_t)(k0 * 64 + sr1) * 64 + sc1 * 8, &sK[0][(w + 4) * 512]);
        GLOAD_LDS16(Vbase + (size_t)sr0 * 2048 + k0 * 64 + sc0 * 8, &sVT[0][w * 512]);
        GLOAD_LDS16(Vbase + (size_t)sr1 * 2048 + k0 * 64 + sc1 * 8, &sVT[0][(w + 4) * 512]);

        for (int kt = k0; kt <= k1; ++kt) {
            const int cur = (kt - k0) & 1;
            if (kt < k1) {
                const int nk = kt + 1;
                GLOAD_LDS16(Kbase + (size_t)(nk * 64 + sr0) * 64 + sc0 * 8, &sK[cur ^ 1][w * 512]);
                GLOAD_LDS16(Kbase + (size_t)(nk * 64 + sr1) * 64 + sc1 * 8, &sK[cur ^ 1][(w + 4) * 512]);
                GLOAD_LDS16(Vbase + (size_t)sr0 * 2048 + nk * 64 + sc0 * 8, &sVT[cur ^ 1][w * 512]);
                GLOAD_LDS16(Vbase + (size_t)sr1 * 2048 + nk * 64 + sc1 * 8, &sVT[cur ^ 1][(w + 4) * 512]);
                VMCNT4();
            } else VMCNT0();
            BAR();

            // ---- S^T[kv][q] = K . Q  (acc init = -FIXED_M) ----
            fv4 st[4];
            __builtin_amdgcn_s_setprio(1);
#pragma unroll
            for (int jf = 0; jf < 4; ++jf) {
                st[jf] = fv4{-FIXED_M, -FIXED_M, -FIXED_M, -FIXED_M};
                const int kr = jf * 16 + l15;
#pragma unroll
                for (int hh = 0; hh < 2; ++hh) {
                    const bv8 ka = *(const bv8*)&sK[cur][kr * 64 + (((hh * 4 + l4) ^ (kr & 7)) * 8)];
                    st[jf] = mfma16(ka, qf[hh], st[jf]);
                }
            }
            __builtin_amdgcn_s_setprio(0);

            // ---- P = exp2(st), causal mask on diag tile; accumulate l ----
            float ps[16];
            const int qg = qrow + l15;
            if (kt == qt) {
#pragma unroll
                for (int jf = 0; jf < 4; ++jf)
#pragma unroll
                    for (int reg = 0; reg < 4; ++reg) {
                        const int kvg = kt * 64 + jf * 16 + l4 * 4 + reg;
                        ps[jf * 4 + reg] = (kvg > qg) ? -30000.f : st[jf][reg];
                    }
            } else {
#pragma unroll
                for (int jf = 0; jf < 4; ++jf)
#pragma unroll
                    for (int reg = 0; reg < 4; ++reg) ps[jf * 4 + reg] = st[jf][reg];
            }
            float la0 = 0.f, la1 = 0.f, la2 = 0.f, la3 = 0.f;
#pragma unroll
            for (int u = 0; u < 16; u += 4) {
                const float p0 = exp2f(ps[u + 0]); ps[u + 0] = p0; la0 += p0;
                const float p1 = exp2f(ps[u + 1]); ps[u + 1] = p1; la1 += p1;
                const float p2 = exp2f(ps[u + 2]); ps[u + 2] = p2; la2 += p2;
                const float p3 = exp2f(ps[u + 3]); ps[u + 3] = p3; la3 += p3;
            }
            l_ += (la0 + la1) + (la2 + la3);

            // ---- P -> LDS (packed b64, swizzled, own-wave region) ----
#pragma unroll
            for (int jf = 0; jf < 4; ++jf) {
                uv4 pk;
#pragma unroll
                for (int reg = 0; reg < 4; ++reg) pk[reg] = f2bf(ps[jf * 4 + reg]);
                const int chunk = jf * 2 + (l4 >> 1);
                *(uv4*)&sP[w][l15 * 64 + ((chunk ^ (l15 & 7)) * 8) + (l4 & 1) * 4] = pk;
            }

            // ---- O += P V ----
            bv8 pa[2];
#pragma unroll
            for (int hh = 0; hh < 2; ++hh)
                pa[hh] = *(const bv8*)&sP[w][l15 * 64 + (((hh * 4 + l4) ^ (l15 & 7)) * 8)];
            __builtin_amdgcn_s_setprio(1);
#pragma unroll
            for (int jf = 0; jf < 4; ++jf) {
                const int dr = jf * 16 + l15;
#pragma unroll
                for (int hh = 0; hh < 2; ++hh) {
                    const bv8 vb = *(const bv8*)&sVT[cur][dr * 64 + (((hh * 4 + l4) ^ (dr & 7)) * 8)];
                    o[jf] = mfma16(pa[hh], vb, o[jf]);
                }
            }
            __builtin_amdgcn_s_setprio(0);
            BAR();
        }

        // ---- per-lane l for q=l15 (sum the 4 disjoint l4 subsets) ----
        l_ += __shfl_xor(l_, 16);
        l_ += __shfl_xor(l_, 32);

        if (!split) {
            const float inv = 1.0f / l_;
            float invq[4];
#pragma unroll
            for (int reg = 0; reg < 4; ++reg) invq[reg] = __shfl(inv, l4 * 4 + reg);
#pragma unroll
            for (int jf = 0; jf < 4; ++jf)
#pragma unroll
                for (int reg = 0; reg < 4; ++reg)
                    outb[(size_t)(b * S_ + qrow + l4 * 4 + reg) * D_ + h * 64 + jf * 16 + l15] =
                        f2bf(o[jf][reg] * invq[reg]);
        } else {
            const int pair = (qt - 16) * 24 + bh;
            if (t == 0)
                sComm = __hip_atomic_fetch_add(&flags[pair], 1, __ATOMIC_RELAXED,
                                               __HIP_MEMORY_SCOPE_AGENT);
            __syncthreads();
            const int old = sComm;
            if (old == 0) {
                // first finisher: publish fp32 partial (O, l), then release +2
#pragma unroll
                for (int jf = 0; jf < 4; ++jf)
#pragma unroll
                    for (int reg = 0; reg < 4; ++reg)
                        scrO[(size_t)pair * 4096 + (w * 16 + l4 * 4 + reg) * 64 + jf * 16 + l15] =
                            o[jf][reg];
                if (l4 == 0) scrL[pair * 64 + w * 16 + l15] = l_;
                __threadfence();
                __syncthreads();
                if (t == 0)
                    __hip_atomic_fetch_add(&flags[pair], 2, __ATOMIC_RELEASE,
                                           __HIP_MEMORY_SCOPE_AGENT);
            } else {
                // last finisher: wait for publish (flag reaches 1+1+2 = 4), merge
                if (t == 0) {
                    while (__hip_atomic_load(&flags[pair], __ATOMIC_ACQUIRE,
                                             __HIP_MEMORY_SCOPE_AGENT) < 4)
                        __builtin_amdgcn_s_sleep(2);
                }
                __syncthreads();
                __threadfence();
                const float lo = scrL[pair * 64 + w * 16 + l15];
                const float inv = 1.0f / (l_ + lo);
                float invq[4];
#pragma unroll
                for (int reg = 0; reg < 4; ++reg) invq[reg] = __shfl(inv, l4 * 4 + reg);
#pragma unroll
                for (int jf = 0; jf < 4; ++jf)
#pragma unroll
                    for (int reg = 0; reg < 4; ++reg) {
                        const float ov =
                            scrO[(size_t)pair * 4096 + (w * 16 + l4 * 4 + reg) * 64 + jf * 16 + l15];
                        outb[(size_t)(b * S_ + qrow + l4 * 4 + reg) * D_ + h * 64 + jf * 16 + l15] =
                            f2bf((o[jf][reg] + ov) * invq[reg]);
                    }
            }
        }
    }
}

// ---------------------------------------------------------------------------
extern "C" void kernel_launch(void* const* d_in, const int* in_sizes, int n_in,
                              void* d_out, int out_size, void* d_ws, size_t ws_size,
                              hipStream_t stream)
{
    const float* hs    = (const float*)d_in[0];
    const float* wqkv  = (const float*)d_in[1];
    const float* bqkv  = (const float*)d_in[2];
    const float* wproj = (const float*)d_in[3];
    const float* bproj = (const float*)d_in[4];
    float* out = (float*)d_out;

    unsigned short* hsb    = (unsigned short*)d_ws;                 // [4096][768]
    unsigned short* wqkvT  = hsb    + (size_t)M_ * D_;              // [2304][768]
    unsigned short* wprojT = wqkvT  + (size_t)N3D * D_;             // [768][768]
    unsigned short* Qb     = wprojT + (size_t)D_ * D_;              // [24][2048][64]
    unsigned short* Kb     = Qb     + (size_t)24 * 2048 * 64;
    unsigned short* VTb    = Kb     + (size_t)24 * 2048 * 64;       // [24][64][2048]
    unsigned short* attnb  = VTb    + (size_t)24 * 2048 * 64;       // [4096][768]
    int*   cnt   = (int*)(attnb + (size_t)M_ * D_);                 // [0]=queue
    int*   flags = cnt + 4;                                         // [384]
    float* scrL  = (float*)(flags + 384);                           // [384][64]
    float* scrO  = (float*)hsb;  // aliases hsb: dead after QKV GEMM; 384*16KB fits exactly

    prep<<<3840, 256, 0, stream>>>(hs, wqkv, wproj, hsb, wqkvT, wprojT, cnt);
    gemm_bf16<true><<<dim3(N3D / 128, M_ / 128), 256, 0, stream>>>(
        hsb, wqkvT, bqkv, nullptr, Qb, Kb, VTb, M_, N3D, D_);
    flash_mfma<<<768, 256, 0, stream>>>(Qb, Kb, VTb, attnb, cnt, flags, scrO, scrL);
    gemm_bf16<false><<<dim3(D_ / 128, M_ / 128), 256, 0, stream>>>(
        attnb, wprojT, bproj, out, nullptr, nullptr, nullptr, M_, D_, D_);
}

// Round 8
// 163.784 us; speedup vs baseline: 1.6868x; 1.6868x over previous
//
#include <hip/hip_runtime.h>
#include <stdint.h>

// GPT-2 attention block, bf16 MFMA. Round 7 (resubmit — R7 bench never ran):
//  REVERT split-kv (device-scope fences thrashed per-XCD L2 -> 3x regression).
//  Flash = R5 structure (full-tile heavy-first queue, fixed-m exp2 softmax)
//  + single-barrier/iter 3-buffer pipeline (vmcnt publish-then-barrier).
//  GEMMs: same single-barrier transform + bijective XCD swizzle.

constexpr int B_  = 2;
constexpr int S_  = 2048;
constexpr int D_  = 768;
constexpr int N3D = 3 * D_;   // 2304
constexpr int M_  = B_ * S_;  // 4096
constexpr int NTILE = 32 * 24;
#define QSCALE 0.1803368801111f   // 1/sqrt(64) * log2(e)
#define FIXED_M 8.0f

typedef __bf16 bv8 __attribute__((ext_vector_type(8)));
typedef float  fv4 __attribute__((ext_vector_type(4)));
typedef unsigned short uv4 __attribute__((ext_vector_type(4)));
typedef unsigned short uv8 __attribute__((ext_vector_type(8)));

__device__ inline unsigned short f2bf(float x) {
    __bf16 b = (__bf16)x;
    return __builtin_bit_cast(unsigned short, b);
}

__device__ inline fv4 mfma16(bv8 a, bv8 b, fv4 c) {
    return __builtin_amdgcn_mfma_f32_16x16x32_bf16(a, b, c, 0, 0, 0);
}

#define GLOAD_LDS16(g, l)                                                        \
    __builtin_amdgcn_global_load_lds(                                            \
        (__attribute__((address_space(1))) void*)(g),                            \
        (__attribute__((address_space(3))) void*)(l), 16, 0, 0)

#define VMCNT4() asm volatile("s_waitcnt vmcnt(4)" ::: "memory")
#define VMCNT0() asm volatile("s_waitcnt vmcnt(0)" ::: "memory")
#define BAR()                                                                    \
    do { asm volatile("" ::: "memory"); __builtin_amdgcn_s_barrier();            \
         asm volatile("" ::: "memory"); } while (0)

// ---------------------------------------------------------------------------
// Fused prep: [0,1536) cvt hs->bf16 ; [1536,3264) wqkv^T ; [3264,3840) wproj^T
// Block 0 resets the flash work-queue counter.
// ---------------------------------------------------------------------------
__global__ __launch_bounds__(256)
void prep(const float* __restrict__ hs, const float* __restrict__ wqkv,
          const float* __restrict__ wproj, unsigned short* __restrict__ hsb,
          unsigned short* __restrict__ wqkvT, unsigned short* __restrict__ wprojT,
          int* __restrict__ cnt)
{
    __shared__ float tl[32][33];
    const int bid = blockIdx.x, t = threadIdx.x;
    if (bid == 0 && t < 4) cnt[t] = 0;

    if (bid < 1536) {
        const size_t i = ((size_t)bid * 256 + t) * 8;
        const float4 a = *(const float4*)&hs[i];
        const float4 b = *(const float4*)&hs[i + 4];
        uv8 o;
        o[0] = f2bf(a.x); o[1] = f2bf(a.y); o[2] = f2bf(a.z); o[3] = f2bf(a.w);
        o[4] = f2bf(b.x); o[5] = f2bf(b.y); o[6] = f2bf(b.z); o[7] = f2bf(b.w);
        *(uv8*)&hsb[i] = o;
        return;
    }

    const float* W;
    unsigned short* WT;
    int K, N, bx, by;
    if (bid < 3264) {
        W = wqkv; WT = wqkvT; K = 768; N = 2304;
        const int b2 = bid - 1536; bx = b2 % 72; by = b2 / 72;
    } else {
        W = wproj; WT = wprojT; K = 768; N = 768;
        const int b2 = bid - 3264; bx = b2 % 24; by = b2 / 24;
    }
    const int n0 = bx * 32, k0 = by * 32;
    {
        const int r = t >> 3, c = (t & 7) * 4;
        const float4 v = *(const float4*)&W[(size_t)(k0 + r) * N + n0 + c];
        tl[r][c + 0] = v.x; tl[r][c + 1] = v.y; tl[r][c + 2] = v.z; tl[r][c + 3] = v.w;
    }
    __syncthreads();
    {
        const int rn = t >> 3, ck = (t & 7) * 4;
        uv4 o;
        o[0] = f2bf(tl[ck + 0][rn]); o[1] = f2bf(tl[ck + 1][rn]);
        o[2] = f2bf(tl[ck + 2][rn]); o[3] = f2bf(tl[ck + 3][rn]);
        *(uv4*)&WT[(size_t)(n0 + rn) * K + k0 + ck] = o;
    }
}

// ---------------------------------------------------------------------------
// bf16 MFMA GEMM, 128x128 tile, BK=32, 3-buffer LDS, 2-deep prefetch,
// SINGLE barrier per K-step: {vmcnt(4) ; BAR ; stage(t+2) ; compute(t)}.
//  - vmcnt(4) before BAR publishes "my tile-t loads landed" (t+1's 4 remain).
//  - BAR proves all waves finished iter t-1 -> buf[(t+2)%3]=buf[(t-1)%3] free.
// Bijective XCD swizzle on flattened block id (nwg % 8 == 0 for both GEMMs).
// ---------------------------------------------------------------------------
template<bool QKV>
__global__ __launch_bounds__(256)
void gemm_bf16(const unsigned short* __restrict__ A, const unsigned short* __restrict__ BT,
               const float* __restrict__ bias, float* __restrict__ Cf,
               unsigned short* __restrict__ Qb, unsigned short* __restrict__ Kb,
               unsigned short* __restrict__ VTb, int M, int N, int K, int gx)
{
    __shared__ unsigned short smem[24576];   // sA[3] | sB[3]; epilogue reuses 32KB
    unsigned short* const sA0 = smem;
    unsigned short* const sB0 = smem + 12288;

    const int t = threadIdx.x, w = t >> 6, lane = t & 63;
    const int l15 = lane & 15, l4 = lane >> 4;
    // XCD swizzle: chunked remap of the flattened id (nwg multiple of 8)
    const int nwg = gridDim.x, cpx = nwg >> 3;
    const int orig = blockIdx.x;
    const int swz = (orig & 7) * cpx + (orig >> 3);
    const int m0 = (swz / gx) * 128, n0 = (swz % gx) * 128;
    const int wr = w >> 1, wc = w & 1;

    fv4 acc[4][4];
#pragma unroll
    for (int i = 0; i < 4; ++i)
#pragma unroll
        for (int j = 0; j < 4; ++j) acc[i][j] = fv4{0.f, 0.f, 0.f, 0.f};

    const int r0 = w * 16 + (lane >> 2);
    const int c0 = (lane & 3) ^ ((r0 >> 1) & 3);
    const int r1 = (w + 4) * 16 + (lane >> 2);
    const int c1 = (lane & 3) ^ ((r1 >> 1) & 3);

    auto stage = [&](int buf, int k0) {
        GLOAD_LDS16(A  + (size_t)(m0 + r0) * K + k0 + c0 * 8, sA0 + buf * 4096 + w * 512);
        GLOAD_LDS16(A  + (size_t)(m0 + r1) * K + k0 + c1 * 8, sA0 + buf * 4096 + (w + 4) * 512);
        GLOAD_LDS16(BT + (size_t)(n0 + r0) * K + k0 + c0 * 8, sB0 + buf * 4096 + w * 512);
        GLOAD_LDS16(BT + (size_t)(n0 + r1) * K + k0 + c1 * 8, sB0 + buf * 4096 + (w + 4) * 512);
    };

    stage(0, 0);
    stage(1, 32);
    const int nt = K >> 5;
    for (int tt = 0; tt < nt; ++tt) {
        if (tt + 1 < nt) VMCNT4(); else VMCNT0();
        BAR();
        if (tt + 2 < nt) stage((tt + 2) % 3, (tt + 2) * 32);
        const int cur = tt % 3;

        bv8 af[4], bf[4];
#pragma unroll
        for (int i = 0; i < 4; ++i) {
            const int r = wr * 64 + i * 16 + l15;
            const int c = l4 ^ ((r >> 1) & 3);
            af[i] = *(const bv8*)&sA0[cur * 4096 + r * 32 + c * 8];
        }
#pragma unroll
        for (int j = 0; j < 4; ++j) {
            const int r = wc * 64 + j * 16 + l15;
            const int c = l4 ^ ((r >> 1) & 3);
            bf[j] = *(const bv8*)&sB0[cur * 4096 + r * 32 + c * 8];
        }
        __builtin_amdgcn_s_setprio(1);
#pragma unroll
        for (int i = 0; i < 4; ++i)
#pragma unroll
            for (int j = 0; j < 4; ++j)
                acc[i][j] = mfma16(af[i], bf[j], acc[i][j]);
        __builtin_amdgcn_s_setprio(0);
    }

    if (QKV) {
        const int sect = n0 / 768;           // uniform per block (768 % 128 == 0)
        const int rem0 = n0 - sect * 768;
        if (sect < 2) {
            __syncthreads();                 // waves may skew: protect smem reuse
            const float qs = (sect == 0) ? QSCALE : 1.0f;
#pragma unroll
            for (int jf = 0; jf < 4; ++jf) {
                const int c = wc * 64 + jf * 16 + l15;
                const float bb = bias[n0 + c];
                const int ch = c >> 3, off = c & 7;
#pragma unroll
                for (int i = 0; i < 4; ++i) {
                    const int rb = wr * 64 + i * 16 + l4 * 4;
#pragma unroll
                    for (int reg = 0; reg < 4; ++reg) {
                        const int r = rb + reg;
                        smem[r * 128 + ((ch ^ (r & 15)) << 3) + off] =
                            f2bf((acc[i][jf][reg] + bb) * qs);
                    }
                }
            }
            __syncthreads();
            unsigned short* const dstQK = (sect == 0) ? Qb : Kb;
            const int brow = m0 >> 11, sbase = m0 & 2047, hb = rem0 >> 6;
#pragma unroll
            for (int u = 0; u < 8; ++u) {
                const int ID = t + 256 * u;
                const int s = ID >> 4, ch = ID & 15;
                const int hh = ch >> 3, dc = ch & 7;
                const uv8 v = *(const uv8*)&smem[s * 128 + ((ch ^ (s & 15)) << 3)];
                const size_t bh = (size_t)brow * 12 + hb + hh;
                *(uv8*)&dstQK[(bh * 2048 + sbase + s) * 64 + dc * 8] = v;
            }
        } else {
#pragma unroll
            for (int jf = 0; jf < 4; ++jf) {
                const int col = n0 + wc * 64 + jf * 16 + l15;
                const float bb = bias[col];
                const int rem = col - 2 * 768;
                const int hh_ = rem >> 6, d = rem & 63;
#pragma unroll
                for (int i = 0; i < 4; ++i) {
                    const int rowb = m0 + wr * 64 + i * 16 + l4 * 4;
                    const size_t bh = (size_t)(rowb >> 11) * 12 + hh_;
                    const int s0 = rowb & 2047;
                    uv4 pk;
#pragma unroll
                    for (int reg = 0; reg < 4; ++reg) pk[reg] = f2bf(acc[i][jf][reg] + bb);
                    *(uv4*)&VTb[(bh * 64 + d) * 2048 + s0] = pk;
                }
            }
        }
    } else {
#pragma unroll
        for (int jf = 0; jf < 4; ++jf) {
            const int col = n0 + wc * 64 + jf * 16 + l15;
            const float bb = bias[col];
#pragma unroll
            for (int i = 0; i < 4; ++i) {
                const int rowb = m0 + wr * 64 + i * 16 + l4 * 4;
#pragma unroll
                for (int reg = 0; reg < 4; ++reg)
                    Cf[(size_t)(rowb + reg) * N + col] = acc[i][jf][reg] + bb;
            }
        }
    }
}

// ---------------------------------------------------------------------------
// Flash attention (causal), S^T-swapped MFMA, FIXED-m exp2 softmax.
// Full-tile work units (qt, bh), heavy-first atomic queue, 512 blocks.
// 3-buffer K/V^T staging, 2-deep prefetch, ONE barrier per kv-iter:
//   { vmcnt(4) ; BAR ; stage(kt+2) ; QK -> exp2 -> sP -> PV }.
// ---------------------------------------------------------------------------
__global__ __launch_bounds__(256)
void flash_mfma(const unsigned short* __restrict__ Qb, const unsigned short* __restrict__ Kb,
                const unsigned short* __restrict__ VTb, unsigned short* __restrict__ outb,
                int* __restrict__ cnt)
{
    __shared__ unsigned short sK [3][64 * 64];
    __shared__ unsigned short sVT[3][64 * 64];
    __shared__ unsigned short sP [4][16 * 64];
    __shared__ int sj;

    const int t = threadIdx.x, w = t >> 6, lane = t & 63;
    const int l15 = lane & 15, l4 = lane >> 4;

    const int sr0 = w * 8 + (lane >> 3), sc0 = (lane & 7) ^ (sr0 & 7);
    const int sr1 = (w + 4) * 8 + (lane >> 3), sc1 = (lane & 7) ^ (sr1 & 7);

    for (;;) {
        if (t == 0) sj = atomicAdd(cnt, 1);
        __syncthreads();
        const int j = sj;
        if (j >= NTILE) return;
        const int qt = 31 - j / 24;
        const int bh = j - (j / 24) * 24;
        const int b = bh / 12, h = bh - b * 12;
        const int qrow = qt * 64 + w * 16;

        const unsigned short* Kbase = Kb  + (size_t)bh * 2048 * 64;
        const unsigned short* Vbase = VTb + (size_t)bh * 64 * 2048;

        auto stage = [&](int buf, int kt) {
            GLOAD_LDS16(Kbase + (size_t)(kt * 64 + sr0) * 64 + sc0 * 8, &sK[buf][w * 512]);
            GLOAD_LDS16(Kbase + (size_t)(kt * 64 + sr1) * 64 + sc1 * 8, &sK[buf][(w + 4) * 512]);
            GLOAD_LDS16(Vbase + (size_t)sr0 * 2048 + kt * 64 + sc0 * 8, &sVT[buf][w * 512]);
            GLOAD_LDS16(Vbase + (size_t)sr1 * 2048 + kt * 64 + sc1 * 8, &sVT[buf][(w + 4) * 512]);
        };

        bv8 qf[2];
        {
            const unsigned short* qp = Qb + ((size_t)bh * 2048 + qrow + l15) * 64 + l4 * 8;
            qf[0] = *(const bv8*)qp;
            qf[1] = *(const bv8*)(qp + 32);
        }

        fv4 o[4];
#pragma unroll
        for (int jf = 0; jf < 4; ++jf) o[jf] = fv4{0.f, 0.f, 0.f, 0.f};
        float l_ = 0.f;

        stage(0, 0);
        if (qt >= 1) stage(1, 1);

        for (int kt = 0; kt <= qt; ++kt) {
            if (kt < qt) VMCNT4(); else VMCNT0();
            BAR();
            if (kt + 2 <= qt) stage((kt + 2) % 3, kt + 2);
            const int cur = kt % 3;

            // ---- S^T[kv][q] = K . Q  (acc init = -FIXED_M) ----
            fv4 st[4];
            __builtin_amdgcn_s_setprio(1);
#pragma unroll
            for (int jf = 0; jf < 4; ++jf) {
                st[jf] = fv4{-FIXED_M, -FIXED_M, -FIXED_M, -FIXED_M};
                const int kr = jf * 16 + l15;
#pragma unroll
                for (int hh = 0; hh < 2; ++hh) {
                    const bv8 ka = *(const bv8*)&sK[cur][kr * 64 + (((hh * 4 + l4) ^ (kr & 7)) * 8)];
                    st[jf] = mfma16(ka, qf[hh], st[jf]);
                }
            }
            __builtin_amdgcn_s_setprio(0);

            // ---- P = exp2(st), causal mask on diag tile; accumulate l ----
            float ps[16];
            const int qg = qrow + l15;
            if (kt == qt) {
#pragma unroll
                for (int jf = 0; jf < 4; ++jf)
#pragma unroll
                    for (int reg = 0; reg < 4; ++reg) {
                        const int kvg = kt * 64 + jf * 16 + l4 * 4 + reg;
                        ps[jf * 4 + reg] = (kvg > qg) ? -30000.f : st[jf][reg];
                    }
            } else {
#pragma unroll
                for (int jf = 0; jf < 4; ++jf)
#pragma unroll
                    for (int reg = 0; reg < 4; ++reg) ps[jf * 4 + reg] = st[jf][reg];
            }
            float la0 = 0.f, la1 = 0.f, la2 = 0.f, la3 = 0.f;
#pragma unroll
            for (int u = 0; u < 16; u += 4) {
                const float p0 = exp2f(ps[u + 0]); ps[u + 0] = p0; la0 += p0;
                const float p1 = exp2f(ps[u + 1]); ps[u + 1] = p1; la1 += p1;
                const float p2 = exp2f(ps[u + 2]); ps[u + 2] = p2; la2 += p2;
                const float p3 = exp2f(ps[u + 3]); ps[u + 3] = p3; la3 += p3;
            }
            l_ += (la0 + la1) + (la2 + la3);

            // ---- P -> LDS (packed b64, swizzled, own-wave region) ----
#pragma unroll
            for (int jf = 0; jf < 4; ++jf) {
                uv4 pk;
#pragma unroll
                for (int reg = 0; reg < 4; ++reg) pk[reg] = f2bf(ps[jf * 4 + reg]);
                const int chunk = jf * 2 + (l4 >> 1);
                *(uv4*)&sP[w][l15 * 64 + ((chunk ^ (l15 & 7)) * 8) + (l4 & 1) * 4] = pk;
            }

            // ---- O += P V ----
            bv8 pa[2];
#pragma unroll
            for (int hh = 0; hh < 2; ++hh)
                pa[hh] = *(const bv8*)&sP[w][l15 * 64 + (((hh * 4 + l4) ^ (l15 & 7)) * 8)];
            __builtin_amdgcn_s_setprio(1);
#pragma unroll
            for (int jf = 0; jf < 4; ++jf) {
                const int dr = jf * 16 + l15;
#pragma unroll
                for (int hh = 0; hh < 2; ++hh) {
                    const bv8 vb = *(const bv8*)&sVT[cur][dr * 64 + (((hh * 4 + l4) ^ (dr & 7)) * 8)];
                    o[jf] = mfma16(pa[hh], vb, o[jf]);
                }
            }
            __builtin_amdgcn_s_setprio(0);
        }

        // ---- epilogue: reduce l across l4 group, normalize, store ----
        l_ += __shfl_xor(l_, 16);
        l_ += __shfl_xor(l_, 32);
        const float inv = 1.0f / l_;
        float invq[4];
#pragma unroll
        for (int reg = 0; reg < 4; ++reg) invq[reg] = __shfl(inv, l4 * 4 + reg);
#pragma unroll
        for (int jf = 0; jf < 4; ++jf)
#pragma unroll
            for (int reg = 0; reg < 4; ++reg)
                outb[(size_t)(b * S_ + qrow + l4 * 4 + reg) * D_ + h * 64 + jf * 16 + l15] =
                    f2bf(o[jf][reg] * invq[reg]);
    }
}

// ---------------------------------------------------------------------------
extern "C" void kernel_launch(void* const* d_in, const int* in_sizes, int n_in,
                              void* d_out, int out_size, void* d_ws, size_t ws_size,
                              hipStream_t stream)
{
    const float* hs    = (const float*)d_in[0];
    const float* wqkv  = (const float*)d_in[1];
    const float* bqkv  = (const float*)d_in[2];
    const float* wproj = (const float*)d_in[3];
    const float* bproj = (const float*)d_in[4];
    float* out = (float*)d_out;

    unsigned short* hsb    = (unsigned short*)d_ws;                 // [4096][768]
    unsigned short* wqkvT  = hsb    + (size_t)M_ * D_;              // [2304][768]
    unsigned short* wprojT = wqkvT  + (size_t)N3D * D_;             // [768][768]
    unsigned short* Qb     = wprojT + (size_t)D_ * D_;              // [24][2048][64]
    unsigned short* Kb     = Qb     + (size_t)24 * 2048 * 64;
    unsigned short* VTb    = Kb     + (size_t)24 * 2048 * 64;       // [24][64][2048]
    unsigned short* attnb  = VTb    + (size_t)24 * 2048 * 64;       // [4096][768]
    int* cnt = (int*)(attnb + (size_t)M_ * D_);

    prep<<<3840, 256, 0, stream>>>(hs, wqkv, wproj, hsb, wqkvT, wprojT, cnt);
    gemm_bf16<true><<<(N3D / 128) * (M_ / 128), 256, 0, stream>>>(
        hsb, wqkvT, bqkv, nullptr, Qb, Kb, VTb, M_, N3D, D_, N3D / 128);
    flash_mfma<<<512, 256, 0, stream>>>(Qb, Kb, VTb, attnb, cnt);
    gemm_bf16<false><<<(D_ / 128) * (M_ / 128), 256, 0, stream>>>(
        attnb, wprojT, bproj, out, nullptr, nullptr, nullptr, M_, D_, D_, D_ / 128);
}